// Round 3
// baseline (102.602 us; speedup 1.0000x reference)
//
#include <hip/hip_runtime.h>

#define BB 8
#define GG 8
#define HH 4
#define KK 8192
#define DD 128
#define RR 32
#define THREADS 256
#define CHUNK 32                 // keys per staged chunk (16 KB)
#define KPB 512                  // keys per block
#define NCHUNK (KPB / CHUNK)     // 16

// LDS 16B-slot layout for a key chunk: slot q (q=0..1023) holds global
// float4 (ki = q>>5, jj = (q&31) ^ (ki&31)) of the chunk -- XOR swizzle so
// that "all lanes read different keys at the same D-chunk" hits banks like
// a linear read (T2 pattern).

__global__ __launch_bounds__(THREADS) void lowrank_scores(
    const float* __restrict__ query,
    const float* __restrict__ key,
    const float* __restrict__ weight,
    float* __restrict__ out)
{
    __shared__ float buf[2][CHUNK * DD];   // 2 x 16 KB key buffers
    __shared__ float qproj[HH][RR];        // 512 B
    __shared__ float u_lds[HH][DD];        // 2 KB

    const int bpbg = KK / KPB;             // 16 blocks per (b,g)
    const int bg   = blockIdx.x / bpbg;
    const int kblk = blockIdx.x % bpbg;
    const int g    = bg & (GG - 1);
    const int tid  = threadIdx.x;
    const int wave = tid >> 6;             // wave w handles head h = w
    const int lane = tid & 63;
    const int dq   = lane >> 4;            // D-quarter (32 floats)
    const int kio  = lane & 15;            // key offset within sub-iter

    // ---- prologue: W -> qproj -> u  (W overlaid into buf[0]: 4096 floats) ----
    float* w_lds = &buf[0][0];             // DD*RR = 4096 floats = 16 KB exactly
    {
        const float4* wg = (const float4*)(weight + (size_t)g * DD * RR);
        float4* wl = (float4*)w_lds;
        for (int i = tid; i < DD * RR / 4; i += THREADS) wl[i] = wg[i];
    }
    __syncthreads();

    if (tid < HH * RR) {
        const int h = tid >> 5, r = tid & (RR - 1);
        const float* qp = query + ((size_t)bg * HH + h) * DD;
        float s = 0.f;
        #pragma unroll 8
        for (int d = 0; d < DD; ++d) s += qp[d] * w_lds[d * RR + r];
        qproj[h][r] = s;
    }
    __syncthreads();

    for (int idx = tid; idx < HH * DD; idx += THREADS) {
        const int h = idx >> 7, d = idx & (DD - 1);
        float s = 0.f;
        #pragma unroll
        for (int rr = 0; rr < RR; ++rr) {
            const int r = (rr + d) & (RR - 1);       // rotated: no bank conflict
            s += qproj[h][r] * w_lds[d * RR + r];
        }
        u_lds[h][d] = s;
    }
    __syncthreads();

    // each lane: u fragment for (head=wave, D-quarter=dq): 8 x float4 = 32 VGPR
    float4 uf[8];
    #pragma unroll
    for (int j = 0; j < 8; ++j)
        uf[j] = *(const float4*)&u_lds[wave][dq * 32 + j * 4];
    __syncthreads();   // done with w_lds (aliases buf[0]) before staging

    // ---- main pipeline ----
    const float* keyb = key + (size_t)bg * KK * DD + (size_t)kblk * KPB * DD;
    float* outb = out + (size_t)bg * HH * KK + (size_t)wave * KK + kblk * KPB;
    const float scale = 0.08838834764831845f;   // 128^-0.5

    float4 regs[4];

    // stage chunk c's global data into regs (swizzled source addresses)
    #define STAGE_LOAD(c)                                                     \
        {                                                                     \
            _Pragma("unroll")                                                 \
            for (int pass = 0; pass < 4; ++pass) {                            \
                const int q  = tid + pass * THREADS;                          \
                const int ki = q >> 5;                                        \
                const int jj = (q & 31) ^ (ki & 31);                          \
                regs[pass] = *(const float4*)(keyb +                          \
                    ((size_t)(c) * CHUNK + ki) * DD + jj * 4);                \
            }                                                                 \
        }

    #define STAGE_WRITE(b)                                                   \
        {                                                                     \
            _Pragma("unroll")                                                 \
            for (int pass = 0; pass < 4; ++pass) {                            \
                const int q = tid + pass * THREADS;                           \
                *(float4*)&buf[b][q * 4] = regs[pass];                        \
            }                                                                 \
        }

    STAGE_LOAD(0);
    STAGE_WRITE(0);
    STAGE_LOAD(1);
    __syncthreads();

    for (int c = 0; c < NCHUNK; ++c) {
        const int cur = c & 1;
        const int nxt = cur ^ 1;
        if (c + 1 < NCHUNK) STAGE_WRITE(nxt);     // regs hold chunk c+1
        if (c + 2 < NCHUNK) STAGE_LOAD(c + 2);    // issue early: latency hides under compute

        // compute chunk c from buf[cur]: 32 keys, 2 sub-iters of 16
        #pragma unroll
        for (int s = 0; s < 2; ++s) {
            const int ki = s * 16 + kio;
            float a = 0.f;
            #pragma unroll
            for (int j = 0; j < 8; ++j) {
                const int jj = dq * 8 + j;
                const int p  = jj ^ (ki & 31);
                const float4 kv = *(const float4*)&buf[cur][(ki * 32 + p) * 4];
                a += kv.x * uf[j].x + kv.y * uf[j].y + kv.z * uf[j].z + kv.w * uf[j].w;
            }
            a += __shfl_xor(a, 16);
            a += __shfl_xor(a, 32);
            if (lane < 16) outb[c * CHUNK + ki] = a * scale;
        }
        __syncthreads();
    }
    #undef STAGE_LOAD
    #undef STAGE_WRITE
}

extern "C" void kernel_launch(void* const* d_in, const int* in_sizes, int n_in,
                              void* d_out, int out_size, void* d_ws, size_t ws_size,
                              hipStream_t stream) {
    const float* query  = (const float*)d_in[0];
    const float* key    = (const float*)d_in[1];
    const float* weight = (const float*)d_in[2];
    float* out = (float*)d_out;

    const int grid = BB * GG * (KK / KPB);   // 1024 blocks = 4 per CU
    lowrank_scores<<<dim3(grid), dim3(THREADS), 0, stream>>>(query, key, weight, out);
}

// Round 4
// 53.567 us; speedup vs baseline: 1.9154x; 1.9154x over previous
//
#include <hip/hip_runtime.h>

#define BB 8
#define GG 8
#define HH 4
#define KK 8192
#define DD 128
#define RR 32
#define THREADS 256
#define KPB 512                     // keys per block
#define KPW (KPB / 4)               // keys per wave = 128
#define NB  (KPW / 8)               // batches per wave = 16 (8 keys each)

#define DOT4(v, u) ((v).x * (u).x + (v).y * (u).y + (v).z * (u).z + (v).w * (u).w)

__global__ __launch_bounds__(THREADS, 4) void lowrank_scores(
    const float* __restrict__ query,
    const float* __restrict__ key,
    const float* __restrict__ weight,
    float* __restrict__ out)
{
    __shared__ float w_lds[DD * RR];   // 16 KB, layout [d][r]
    __shared__ float qproj[HH][RR];
    __shared__ float u_lds[HH][DD];

    const int bpbg = KK / KPB;         // 16 blocks per (b,g)
    const int bg   = blockIdx.x / bpbg;
    const int kblk = blockIdx.x % bpbg;
    const int g    = bg & (GG - 1);
    const int tid  = threadIdx.x;

    // ---- prologue: u[h] = W (W^T q[h]) ----
    {
        const float4* wg = (const float4*)(weight + (size_t)g * DD * RR);
        float4* wl = (float4*)w_lds;
        for (int i = tid; i < DD * RR / 4; i += THREADS) wl[i] = wg[i];
    }
    __syncthreads();

    if (tid < HH * RR) {
        const int h = tid >> 5, r = tid & (RR - 1);
        const float* qp = query + ((size_t)bg * HH + h) * DD;
        float s = 0.f;
        #pragma unroll 8
        for (int d = 0; d < DD; ++d) s += qp[d] * w_lds[d * RR + r];
        qproj[h][r] = s;
    }
    __syncthreads();

    for (int idx = tid; idx < HH * DD; idx += THREADS) {
        const int h = idx >> 7, d = idx & (DD - 1);
        float s = 0.f;
        #pragma unroll
        for (int rr = 0; rr < RR; ++rr) {
            const int r = (rr + d) & (RR - 1);   // rotated: bank-conflict-free
            s += qproj[h][r] * w_lds[d * RR + r];
        }
        u_lds[h][d] = s;
    }
    __syncthreads();

    // ---- main loop: 8 lanes per key, lane owns chunks {(l&7)+8j, j=0..3} ----
    const int lane = tid & 63;
    const int wave = tid >> 6;
    const int l7   = lane & 7;         // position within key-group
    const int kg   = lane >> 3;        // which of 8 concurrent keys

    float4 uf[HH][4];                  // 64 VGPR: u fragments (broadcast reads)
    #pragma unroll
    for (int h = 0; h < HH; ++h)
        #pragma unroll
        for (int j = 0; j < 4; ++j)
            uf[h][j] = *(const float4*)&u_lds[h][(l7 + 8 * j) * 4];

    // lane's base: key row (kbase + kg), float offset l7*4; chunk j adds 32j
    const float* keyb = key + ((size_t)bg * KK + (size_t)kblk * KPB
                               + (size_t)wave * KPW + kg) * DD + l7 * 4;
    float* outb = out + (size_t)bg * HH * KK + (size_t)kblk * KPB + wave * KPW;
    const float scale = 0.08838834764831845f;   // 128^-0.5

    float4 kr[2][4];

    #define LOADB(s, bt)                                                      \
        {                                                                     \
            const float* p = keyb + (size_t)(bt) * (8 * DD);                  \
            kr[s][0] = *(const float4*)(p);                                   \
            kr[s][1] = *(const float4*)(p + 32);                              \
            kr[s][2] = *(const float4*)(p + 64);                              \
            kr[s][3] = *(const float4*)(p + 96);                              \
        }

    #define COMPUTEB(s, bt)                                                   \
        {                                                                     \
            float a0 = DOT4(kr[s][0], uf[0][0]) + DOT4(kr[s][1], uf[0][1])    \
                     + DOT4(kr[s][2], uf[0][2]) + DOT4(kr[s][3], uf[0][3]);   \
            float a1 = DOT4(kr[s][0], uf[1][0]) + DOT4(kr[s][1], uf[1][1])    \
                     + DOT4(kr[s][2], uf[1][2]) + DOT4(kr[s][3], uf[1][3]);   \
            float a2 = DOT4(kr[s][0], uf[2][0]) + DOT4(kr[s][1], uf[2][1])    \
                     + DOT4(kr[s][2], uf[2][2]) + DOT4(kr[s][3], uf[2][3]);   \
            float a3 = DOT4(kr[s][0], uf[3][0]) + DOT4(kr[s][1], uf[3][1])    \
                     + DOT4(kr[s][2], uf[3][2]) + DOT4(kr[s][3], uf[3][3]);   \
            a0 += __shfl_xor(a0, 1); a1 += __shfl_xor(a1, 1);                 \
            a2 += __shfl_xor(a2, 1); a3 += __shfl_xor(a3, 1);                 \
            a0 += __shfl_xor(a0, 2); a1 += __shfl_xor(a1, 2);                 \
            a2 += __shfl_xor(a2, 2); a3 += __shfl_xor(a3, 2);                 \
            a0 += __shfl_xor(a0, 4); a1 += __shfl_xor(a1, 4);                 \
            a2 += __shfl_xor(a2, 4); a3 += __shfl_xor(a3, 4);                 \
            if (l7 == 0) {                                                    \
                const int kw = (bt) * 8 + kg;                                 \
                outb[(size_t)0 * KK + kw] = a0 * scale;                       \
                outb[(size_t)1 * KK + kw] = a1 * scale;                       \
                outb[(size_t)2 * KK + kw] = a2 * scale;                       \
                outb[(size_t)3 * KK + kw] = a3 * scale;                       \
            }                                                                 \
        }

    LOADB(0, 0);
    #pragma unroll
    for (int bt = 0; bt < NB; ++bt) {
        if (bt + 1 < NB) LOADB((bt + 1) & 1, bt + 1);
        COMPUTEB(bt & 1, bt);
    }
    #undef LOADB
    #undef COMPUTEB
}

extern "C" void kernel_launch(void* const* d_in, const int* in_sizes, int n_in,
                              void* d_out, int out_size, void* d_ws, size_t ws_size,
                              hipStream_t stream) {
    const float* query  = (const float*)d_in[0];
    const float* key    = (const float*)d_in[1];
    const float* weight = (const float*)d_in[2];
    float* out = (float*)d_out;

    const int grid = BB * GG * (KK / KPB);   // 1024 blocks = 4 per CU (one round)
    lowrank_scores<<<dim3(grid), dim3(THREADS), 0, stream>>>(query, key, weight, out);
}